// Round 15
// baseline (299.256 us; speedup 1.0000x reference)
//
#include <hip/hip_runtime.h>

static constexpr int NN = 100000;
static constexpr int NE = 1600000;
static constexpr int NBUK = (NN + 1023) / 1024;      // 98 buckets of 1024 nodes
static constexpr int BCAP = 20480;                   // bucket capacity (mean 16384 + 32 sigma)
static constexpr int SC_BLOCKS = 400;
static constexpr int SC_CH = NE / SC_BLOCKS;         // 4000 edges per block

typedef float     f32x4  __attribute__((ext_vector_type(4)));
typedef _Float16  f16x8  __attribute__((ext_vector_type(8)));

static constexpr float LO_SCALE  = 16384.0f;          // 2^14: keeps w-lo in fp16 normal range
static constexpr float LO_USCALE = 1.0f / 16384.0f;

// fp16 pack/unpack (2 elems per 32-bit word)
__device__ __forceinline__ unsigned pkh(float x, float y){
  unsigned short a = __builtin_bit_cast(unsigned short, (_Float16)x);
  unsigned short b = __builtin_bit_cast(unsigned short, (_Float16)y);
  return (unsigned)a | ((unsigned)b << 16);
}
__device__ __forceinline__ float2 uph(unsigned u){
  _Float16 a = __builtin_bit_cast(_Float16, (unsigned short)(u & 0xffffu));
  _Float16 b = __builtin_bit_cast(_Float16, (unsigned short)(u >> 16));
  return make_float2((float)a, (float)b);
}

// ------------- weight packing: per half-stage contiguous 32KB, hi/lo interleaved -------------
// layout: P[hidx*16384 + (kt*4+ct4)*1024 + hl*512 + lane*8 + j]
// fragment (kt,ct): lane holds B[kt*32+(lane>>4)*8+j][ct*16+(lane&15)], j=0..7
__global__ void k_pack(const float* __restrict__ w11, const float* __restrict__ w12,
                       const float* __restrict__ w21, const float* __restrict__ w22,
                       const float* __restrict__ wm1, const float* __restrict__ wm2,
                       unsigned short* __restrict__ p11, unsigned short* __restrict__ p12,
                       unsigned short* __restrict__ p21, unsigned short* __restrict__ p22,
                       unsigned short* __restrict__ pm1, unsigned short* __restrict__ pm2){
  int b = blockIdx.x, lane = threadIdx.x;
  const float* W; unsigned short* P; int NCT, f;
  if (b < 160){
    int m = b >> 5; f = b & 31; NCT = 8;
    W = (m==0)?w11:(m==1)?w12:(m==2)?w21:(m==3)?w22:wm1;
    P = (m==0)?p11:(m==1)?p12:(m==2)?p21:(m==3)?p22:pm1;
  } else { f = b - 160; NCT = 4; W = wm2; P = pm2; }
  int NC = NCT * 16;
  int kt = f / NCT, ct = f % NCT;
  int hidx = ct >> 2, ct4 = ct & 3;
  int k0 = kt*32 + ((lane>>4)*8), col = ct*16 + (lane&15);
  unsigned short* dh = P + (hidx<<14) + ((kt*4+ct4)<<10) + (lane<<3);
  unsigned short* dl = dh + 512;
  #pragma unroll
  for (int j=0;j<8;j++){
    float v = W[(size_t)(k0+j)*NC + col];
    _Float16 h = (_Float16)v;
    _Float16 l = (_Float16)((v - (float)h) * LO_SCALE);
    dh[j] = __builtin_bit_cast(unsigned short, h);
    dl[j] = __builtin_bit_cast(unsigned short, l);
  }
}

// ---------------- f32 -> fp16 convert ----------------
__global__ void k_cvt(const float* __restrict__ x, unsigned* __restrict__ xh, int n4){
  int i = blockIdx.x*256 + threadIdx.x;
  if (i < n4){
    float4 v = reinterpret_cast<const float4*>(x)[i];
    uint2 o; o.x = pkh(v.x, v.y); o.y = pkh(v.z, v.w);
    reinterpret_cast<uint2*>(xh)[i] = o;
  }
}

// ---------------- CSR build: fixed-capacity buckets, no histogram pass ----------------
__global__ __launch_bounds__(256) void k_scatter1(const int* __restrict__ src,
                                                  const int* __restrict__ dst,
                                                  int* __restrict__ gbcur,
                                                  unsigned* __restrict__ tmp){
  __shared__ int hc[NBUK];
  __shared__ int hb[NBUK];
  int blk = blockIdx.x, t = threadIdx.x;
  int e0 = blk * SC_CH, e1 = e0 + SC_CH;
  for (int i=t;i<NBUK;i+=256) hc[i]=0;
  __syncthreads();
  for (int e=e0+t; e<e1; e+=256) atomicAdd(&hc[((unsigned)dst[e])>>10], 1);
  __syncthreads();
  for (int i=t;i<NBUK;i+=256){ int c = hc[i]; hb[i] = c ? atomicAdd(&gbcur[i], c) : 0; }
  __syncthreads();
  for (int i=t;i<NBUK;i+=256) hc[i]=0;
  __syncthreads();
  for (int e=e0+t; e<e1; e+=256){
    unsigned d = (unsigned)dst[e]; unsigned b = d>>10;
    int pos = hb[b] + atomicAdd(&hc[b], 1);
    if (pos < BCAP)
      tmp[(size_t)b*BCAP + pos] = ((unsigned)src[e] << 10) | (d & 1023u);
  }
}

// one block per 1024-node bucket: LDS counting sort -> eidx, emits deg & rs
__global__ __launch_bounds__(256) void k_fill2(const unsigned* __restrict__ tmp,
                                               const int* __restrict__ gbcur,
                                               int* __restrict__ eidx,
                                               int* __restrict__ rs, int* __restrict__ deg, int N){
  __shared__ int lh[1024];  // per-local-node count
  __shared__ int ls[1024];  // exclusive prefix
  __shared__ int lc[1024];  // placement cursor
  __shared__ int wsum[256];
  int b = blockIdx.x, t = threadIdx.x;
  int base = b*BCAP;
  int cnt = gbcur[b]; if (cnt > BCAP) cnt = BCAP;
  int nb0 = b*1024;
  for (int i=t;i<1024;i+=256){ lh[i]=0; lc[i]=0; }
  __syncthreads();
  for (int i=t; i<cnt; i+=256) atomicAdd(&lh[tmp[(size_t)base+i] & 1023u], 1);
  __syncthreads();
  int v4[4]; int sum = 0;
  #pragma unroll
  for (int j=0;j<4;j++){ v4[j] = lh[t*4+j]; sum += v4[j]; }
  wsum[t] = sum; __syncthreads();
  for (int off=1; off<256; off<<=1){
    int u = 0; if (t>=off) u = wsum[t-off];
    __syncthreads(); wsum[t] += u; __syncthreads();
  }
  int run = wsum[t] - sum;   // exclusive base for this thread's 4 nodes
  #pragma unroll
  for (int j=0;j<4;j++){ ls[t*4+j] = run; run += v4[j]; }
  __syncthreads();
  #pragma unroll
  for (int j=0;j<4;j++){
    int node = nb0 + t*4 + j;
    if (node < N){ deg[node] = v4[j]; rs[node] = base + ls[t*4+j]; }
  }
  __syncthreads();
  for (int i=t; i<cnt; i+=256){
    unsigned e = tmp[(size_t)base+i];
    int local = e & 1023u;
    int pos = atomicAdd(&lc[local], 1);
    eidx[base + ls[local] + pos] = (int)(e >> 10);
  }
}

// ---- aggregation (fp16 rows, f32 accum): out = (1+eps)*in + sum_{nbr} in[nbr] ----
__global__ __launch_bounds__(256) void k_agg(const unsigned* __restrict__ inp,
                                             unsigned* __restrict__ out,
                                             const float* __restrict__ epsp,
                                             const int* __restrict__ rs, const int* __restrict__ deg,
                                             const int* __restrict__ eidx, int N){
  int gw = (blockIdx.x*256 + threadIdx.x) >> 6;
  int lane = threadIdx.x & 63;
  if (gw >= N) return;
  float sc = 1.0f + *epsp;
  float2 v = uph(inp[(size_t)gw*64 + lane]);
  float a0 = sc * v.x, a1 = sc * v.y;
  int beg = rs[gw], d = deg[gw];
  int i = 0;
  for (; i+8 <= d; i += 8){
    unsigned u[8];
    #pragma unroll
    for (int j=0;j<8;j++) u[j] = inp[(size_t)eidx[beg+i+j]*64 + lane];
    #pragma unroll
    for (int j=0;j<8;j++){ float2 f = uph(u[j]); a0 += f.x; a1 += f.y; }
  }
  for (; i < d; ++i){
    float2 u = uph(inp[(size_t)eidx[beg+i]*64 + lane]);
    a0 += u.x; a1 += u.y;
  }
  out[(size_t)gw*64 + lane] = pkh(a0, a1);
}

// ---------------- MFMA MLP helpers (fp16 datapath, M=32/wave) ----------------
// A frag: row = lane&15, k = (lane>>4)*8 + j ; D: col = lane&15, row = (lane>>4)*4 + r
static constexpr int HSTR = 136;           // fp16 row stride in halves
static constexpr int WSLICE = 32*HSTR;     // 32 rows per wave = 8704 B

__device__ __forceinline__ void load_a_glob2(const _Float16* __restrict__ t, int rbase,
                                             int lane, int N, f16x8 a[2][4]){
  #pragma unroll
  for (int ms=0; ms<2; ++ms){
    int row = rbase + ms*16 + (lane & 15); if (row >= N) row = N - 1;
    const _Float16* ap = t + (size_t)row*128 + ((lane>>4)*8);
    #pragma unroll
    for (int kt=0;kt<4;kt++) a[ms][kt] = *reinterpret_cast<const f16x8*>(ap + kt*32);
  }
}
__device__ __forceinline__ void load_a_lds2(const _Float16* slice, int lane, f16x8 a[2][4]){
  int ko = (lane>>4)*8;
  #pragma unroll
  for (int ms=0; ms<2; ++ms){
    const _Float16* rp = slice + (ms*16 + (lane&15))*HSTR + ko;
    #pragma unroll
    for (int kt=0;kt<4;kt++) a[ms][kt] = *reinterpret_cast<const f16x8*>(rp + kt*32);
  }
}

// one 64-col half: out cols [hidx*64, hidx*64+64), relu -> fp16 slice
__device__ __forceinline__ void half_relu(const f16x8 a[2][4],
                                          const unsigned short* __restrict__ w,
                                          const float* __restrict__ bias,
                                          _Float16* slice, int lane, int hidx){
  const unsigned short* wb = w + (hidx<<14);
  int r0 = (lane>>4)*4, col0 = lane & 15;
  #pragma unroll
  for (int ct4=0; ct4<4; ++ct4){
    f32x4 c0={0.f,0.f,0.f,0.f}, c1={0.f,0.f,0.f,0.f};
    f32x4 d0={0.f,0.f,0.f,0.f}, d1={0.f,0.f,0.f,0.f};
    __builtin_amdgcn_s_setprio(1);
    #pragma unroll
    for (int kt=0; kt<4; ++kt){
      const f16x8 bh = *reinterpret_cast<const f16x8*>(wb + ((kt*4+ct4)<<10) + (lane<<3));
      const f16x8 bl = *reinterpret_cast<const f16x8*>(wb + ((kt*4+ct4)<<10) + 512 + (lane<<3));
      c0 = __builtin_amdgcn_mfma_f32_16x16x32_f16(a[0][kt], bh, c0, 0,0,0);
      c1 = __builtin_amdgcn_mfma_f32_16x16x32_f16(a[1][kt], bh, c1, 0,0,0);
      d0 = __builtin_amdgcn_mfma_f32_16x16x32_f16(a[0][kt], bl, d0, 0,0,0);
      d1 = __builtin_amdgcn_mfma_f32_16x16x32_f16(a[1][kt], bl, d1, 0,0,0);
    }
    __builtin_amdgcn_s_setprio(0);
    float bv = bias[hidx*64 + ct4*16 + col0];
    int cb = hidx*64 + ct4*16 + col0;
    #pragma unroll
    for (int r=0;r<4;r++){
      float v0 = fmaxf(c0[r] + d0[r]*LO_USCALE + bv, 0.f);
      float v1 = fmaxf(c1[r] + d1[r]*LO_USCALE + bv, 0.f);
      slice[(r0+r)*HSTR + cb]      = (_Float16)v0;
      slice[(16+r0+r)*HSTR + cb]   = (_Float16)v1;
    }
  }
}

// head half (64 cols): sigmoid -> f32 staging (stride 68) overlaid on slice
__device__ __forceinline__ void head_sig(const f16x8 a[2][4],
                                         const unsigned short* __restrict__ w,
                                         const float* __restrict__ bias,
                                         float* fs, int lane){
  int r0 = (lane>>4)*4, col0 = lane & 15;
  #pragma unroll
  for (int ct4=0; ct4<4; ++ct4){
    f32x4 c0={0.f,0.f,0.f,0.f}, c1={0.f,0.f,0.f,0.f};
    f32x4 d0={0.f,0.f,0.f,0.f}, d1={0.f,0.f,0.f,0.f};
    __builtin_amdgcn_s_setprio(1);
    #pragma unroll
    for (int kt=0; kt<4; ++kt){
      const f16x8 bh = *reinterpret_cast<const f16x8*>(w + ((kt*4+ct4)<<10) + (lane<<3));
      const f16x8 bl = *reinterpret_cast<const f16x8*>(w + ((kt*4+ct4)<<10) + 512 + (lane<<3));
      c0 = __builtin_amdgcn_mfma_f32_16x16x32_f16(a[0][kt], bh, c0, 0,0,0);
      c1 = __builtin_amdgcn_mfma_f32_16x16x32_f16(a[1][kt], bh, c1, 0,0,0);
      d0 = __builtin_amdgcn_mfma_f32_16x16x32_f16(a[0][kt], bl, d0, 0,0,0);
      d1 = __builtin_amdgcn_mfma_f32_16x16x32_f16(a[1][kt], bl, d1, 0,0,0);
    }
    __builtin_amdgcn_s_setprio(0);
    float bv = bias[ct4*16 + col0];
    int cb = ct4*16 + col0;
    #pragma unroll
    for (int r=0;r<4;r++){
      float z0 = c0[r] + d0[r]*LO_USCALE + bv;
      float z1 = c1[r] + d1[r]*LO_USCALE + bv;
      fs[(r0+r)*68 + cb]    = 1.0f / (1.0f + __expf(-z0));
      fs[(16+r0+r)*68 + cb] = 1.0f / (1.0f + __expf(-z1));
    }
  }
}

// ------------- layer-1 MLP: h1 = relu(relu(t@w1+b1)@w2+b2), fp16 in/out, barrier-free -------------
__global__ __launch_bounds__(256) void k_mlp1(const _Float16* __restrict__ t,
    const unsigned short* __restrict__ w1, const float* __restrict__ b1,
    const unsigned short* __restrict__ w2, const float* __restrict__ b2,
    unsigned* __restrict__ h, int N){
  __shared__ _Float16 lds[4*WSLICE];
  int tid = threadIdx.x, lane = tid & 63, wv = tid >> 6;
  _Float16* slice = lds + wv*WSLICE;
  int rbase = blockIdx.x*128 + wv*32;
  f16x8 a[2][4];
  load_a_glob2(t, rbase, lane, N, a);
  half_relu(a, w1, b1, slice, lane, 0);
  half_relu(a, w1, b1, slice, lane, 1);
  load_a_lds2(slice, lane, a);
  half_relu(a, w2, b2, slice, lane, 0);
  half_relu(a, w2, b2, slice, lane, 1);
  for (int i=lane; i < 32*32; i += 64){
    int r = i >> 5, c = i & 31;
    if (rbase + r < N)
      reinterpret_cast<uint2*>(h)[(size_t)(rbase + r)*32 + c] =
        *reinterpret_cast<const uint2*>(slice + r*HSTR + c*4);
  }
}

// ------- layer-2 MLP + head fused: out = sigmoid(mlp_head(relu(mlp2(t2)))), barrier-free -------
__global__ __launch_bounds__(256) void k_mlp2_head(const _Float16* __restrict__ t,
    const unsigned short* __restrict__ w1, const float* __restrict__ b1,
    const unsigned short* __restrict__ w2, const float* __restrict__ b2,
    const unsigned short* __restrict__ w3, const float* __restrict__ b3,
    const unsigned short* __restrict__ w4, const float* __restrict__ b4,
    float* __restrict__ out, int N){
  __shared__ _Float16 lds[4*WSLICE];
  int tid = threadIdx.x, lane = tid & 63, wv = tid >> 6;
  _Float16* slice = lds + wv*WSLICE;
  int rbase = blockIdx.x*128 + wv*32;
  f16x8 a[2][4];
  load_a_glob2(t, rbase, lane, N, a);
  half_relu(a, w1, b1, slice, lane, 0);
  half_relu(a, w1, b1, slice, lane, 1);
  load_a_lds2(slice, lane, a);
  half_relu(a, w2, b2, slice, lane, 0);
  half_relu(a, w2, b2, slice, lane, 1);
  load_a_lds2(slice, lane, a);
  half_relu(a, w3, b3, slice, lane, 0);
  half_relu(a, w3, b3, slice, lane, 1);
  load_a_lds2(slice, lane, a);
  float* fs = reinterpret_cast<float*>(slice);  // [32][68] f32 = 8704 B = slice
  head_sig(a, w4, b4, fs, lane);
  for (int i=lane; i < 32*16; i += 64){
    int r = i >> 4, c = i & 15;
    if (rbase + r < N){
      f32x4 o = *reinterpret_cast<const f32x4*>(fs + r*68 + c*4);
      __builtin_nontemporal_store(o,
        reinterpret_cast<f32x4*>(out) + (size_t)(rbase + r)*16 + c);   // final out: never re-read
    }
  }
}

// ---------------- host launch ----------------
extern "C" void kernel_launch(void* const* d_in, const int* in_sizes, int n_in,
                              void* d_out, int out_size, void* d_ws, size_t ws_size,
                              hipStream_t stream) {
  const float* x   = (const float*)d_in[0];
  const int*   src = (const int*)  d_in[1];
  const int*   dst = (const int*)  d_in[2];
  const float* eps1= (const float*)d_in[3];
  const float* eps2= (const float*)d_in[4];
  const float* w11 = (const float*)d_in[5];  const float* b11 = (const float*)d_in[6];
  const float* w12 = (const float*)d_in[7];  const float* b12 = (const float*)d_in[8];
  const float* w21 = (const float*)d_in[9];  const float* b21 = (const float*)d_in[10];
  const float* w22 = (const float*)d_in[11]; const float* b22 = (const float*)d_in[12];
  const float* wm1 = (const float*)d_in[13]; const float* bm1 = (const float*)d_in[14];
  const float* wm2 = (const float*)d_in[15]; const float* bm2 = (const float*)d_in[16];

  char* ws = (char*)d_ws;
  size_t off = 0;
  auto alloc = [&](size_t bytes) -> void* {
    void* p = ws + off;
    off = (off + bytes + 255) & ~(size_t)255;
    return p;
  };
  unsigned* xh  = (unsigned*)alloc((size_t)NN*64*4);          // x as fp16 [N][128]
  unsigned* B0  = (unsigned*)alloc((size_t)NN*64*4);          // agg out fp16 (t1 / t2)
  unsigned* h1h = (unsigned*)alloc((size_t)NN*64*4);          // h1 fp16
  unsigned* tmp = (unsigned*)alloc((size_t)NBUK*BCAP*4);      // bucketed (src<<10 | dst&1023)
  int* eidx = (int*)alloc((size_t)NBUK*BCAP*4);
  int* deg  = (int*)alloc((size_t)NN*4);
  int* rs   = (int*)alloc((size_t)NN*4);
  int* gbcur= (int*)alloc((size_t)NBUK*4);
  unsigned short* p11 = (unsigned short*)alloc(128*128*2*2);
  unsigned short* p12 = (unsigned short*)alloc(128*128*2*2);
  unsigned short* p21 = (unsigned short*)alloc(128*128*2*2);
  unsigned short* p22 = (unsigned short*)alloc(128*128*2*2);
  unsigned short* pm1 = (unsigned short*)alloc(128*128*2*2);
  unsigned short* pm2 = (unsigned short*)alloc(128*64*2*2);
  if (off > ws_size) return;   // visible failure if workspace too small

  hipMemsetAsync(gbcur, 0, (size_t)NBUK*4, stream);

  k_pack<<<176, 64, 0, stream>>>(w11,w12,w21,w22,wm1,wm2, p11,p12,p21,p22,pm1,pm2);
  k_cvt<<<(NN*32 + 255)/256, 256, 0, stream>>>(x, xh, NN*32);
  k_scatter1<<<SC_BLOCKS, 256, 0, stream>>>(src, dst, gbcur, tmp);
  k_fill2<<<NBUK, 256, 0, stream>>>(tmp, gbcur, eidx, rs, deg, NN);

  int mgrid = (NN + 127) / 128;   // 782 blocks x 256 threads (4 waves, 32 rows each)
  // layer 1
  k_agg<<<(NN+3)/4, 256, 0, stream>>>(xh, B0, eps1, rs, deg, eidx, NN);
  k_mlp1<<<mgrid, 256, 0, stream>>>((const _Float16*)B0, p11, b11, p12, b12, h1h, NN);
  // layer 2 + head
  k_agg<<<(NN+3)/4, 256, 0, stream>>>(h1h, B0, eps2, rs, deg, eidx, NN);
  k_mlp2_head<<<mgrid, 256, 0, stream>>>((const _Float16*)B0, p21, b21, p22, b22,
                                         pm1, bm1, pm2, bm2, (float*)d_out, NN);
}

// Round 16
// 293.145 us; speedup vs baseline: 1.0208x; 1.0208x over previous
//
#include <hip/hip_runtime.h>

static constexpr int NN = 100000;
static constexpr int NE = 1600000;
static constexpr int NBUK = (NN + 1023) / 1024;      // 98 buckets of 1024 nodes
static constexpr int BCAP = 20480;                   // bucket capacity (mean 16384 + 32 sigma)
static constexpr int SC_BLOCKS = 400;
static constexpr int SC_CH = NE / SC_BLOCKS;         // 4000 edges per block

typedef float     f32x4  __attribute__((ext_vector_type(4)));
typedef _Float16  f16x8  __attribute__((ext_vector_type(8)));

static constexpr float LO_SCALE  = 16384.0f;          // 2^14: keeps w-lo in fp16 normal range
static constexpr float LO_USCALE = 1.0f / 16384.0f;

// fp16 pack/unpack (2 elems per 32-bit word)
__device__ __forceinline__ unsigned pkh(float x, float y){
  unsigned short a = __builtin_bit_cast(unsigned short, (_Float16)x);
  unsigned short b = __builtin_bit_cast(unsigned short, (_Float16)y);
  return (unsigned)a | ((unsigned)b << 16);
}
__device__ __forceinline__ float2 uph(unsigned u){
  _Float16 a = __builtin_bit_cast(_Float16, (unsigned short)(u & 0xffffu));
  _Float16 b = __builtin_bit_cast(_Float16, (unsigned short)(u >> 16));
  return make_float2((float)a, (float)b);
}

// ------------- weight packing: per half-stage contiguous 32KB, hi/lo interleaved -------------
// layout: P[hidx*16384 + (kt*4+ct4)*1024 + hl*512 + lane*8 + j]
// fragment (kt,ct): lane holds B[kt*32+(lane>>4)*8+j][ct*16+(lane&15)], j=0..7
__global__ void k_pack(const float* __restrict__ w11, const float* __restrict__ w12,
                       const float* __restrict__ w21, const float* __restrict__ w22,
                       const float* __restrict__ wm1, const float* __restrict__ wm2,
                       unsigned short* __restrict__ p11, unsigned short* __restrict__ p12,
                       unsigned short* __restrict__ p21, unsigned short* __restrict__ p22,
                       unsigned short* __restrict__ pm1, unsigned short* __restrict__ pm2){
  int b = blockIdx.x, lane = threadIdx.x;
  const float* W; unsigned short* P; int NCT, f;
  if (b < 160){
    int m = b >> 5; f = b & 31; NCT = 8;
    W = (m==0)?w11:(m==1)?w12:(m==2)?w21:(m==3)?w22:wm1;
    P = (m==0)?p11:(m==1)?p12:(m==2)?p21:(m==3)?p22:pm1;
  } else { f = b - 160; NCT = 4; W = wm2; P = pm2; }
  int NC = NCT * 16;
  int kt = f / NCT, ct = f % NCT;
  int hidx = ct >> 2, ct4 = ct & 3;
  int k0 = kt*32 + ((lane>>4)*8), col = ct*16 + (lane&15);
  unsigned short* dh = P + (hidx<<14) + ((kt*4+ct4)<<10) + (lane<<3);
  unsigned short* dl = dh + 512;
  #pragma unroll
  for (int j=0;j<8;j++){
    float v = W[(size_t)(k0+j)*NC + col];
    _Float16 h = (_Float16)v;
    _Float16 l = (_Float16)((v - (float)h) * LO_SCALE);
    dh[j] = __builtin_bit_cast(unsigned short, h);
    dl[j] = __builtin_bit_cast(unsigned short, l);
  }
}

// ---------------- f32 -> fp16 convert ----------------
__global__ void k_cvt(const float* __restrict__ x, unsigned* __restrict__ xh, int n4){
  int i = blockIdx.x*256 + threadIdx.x;
  if (i < n4){
    float4 v = reinterpret_cast<const float4*>(x)[i];
    uint2 o; o.x = pkh(v.x, v.y); o.y = pkh(v.z, v.w);
    reinterpret_cast<uint2*>(xh)[i] = o;
  }
}

// ---------------- CSR build: fixed-capacity buckets, no histogram pass ----------------
__global__ __launch_bounds__(256) void k_scatter1(const int* __restrict__ src,
                                                  const int* __restrict__ dst,
                                                  int* __restrict__ gbcur,
                                                  unsigned* __restrict__ tmp){
  __shared__ int hc[NBUK];
  __shared__ int hb[NBUK];
  int blk = blockIdx.x, t = threadIdx.x;
  int e0 = blk * SC_CH, e1 = e0 + SC_CH;
  for (int i=t;i<NBUK;i+=256) hc[i]=0;
  __syncthreads();
  for (int e=e0+t; e<e1; e+=256) atomicAdd(&hc[((unsigned)dst[e])>>10], 1);
  __syncthreads();
  for (int i=t;i<NBUK;i+=256){ int c = hc[i]; hb[i] = c ? atomicAdd(&gbcur[i], c) : 0; }
  __syncthreads();
  for (int i=t;i<NBUK;i+=256) hc[i]=0;
  __syncthreads();
  for (int e=e0+t; e<e1; e+=256){
    unsigned d = (unsigned)dst[e]; unsigned b = d>>10;
    int pos = hb[b] + atomicAdd(&hc[b], 1);
    if (pos < BCAP)
      tmp[(size_t)b*BCAP + pos] = ((unsigned)src[e] << 10) | (d & 1023u);
  }
}

// one block per 1024-node bucket: LDS counting sort -> eidx, emits deg & rs
__global__ __launch_bounds__(256) void k_fill2(const unsigned* __restrict__ tmp,
                                               const int* __restrict__ gbcur,
                                               int* __restrict__ eidx,
                                               int* __restrict__ rs, int* __restrict__ deg, int N){
  __shared__ int lh[1024];  // per-local-node count
  __shared__ int ls[1024];  // exclusive prefix
  __shared__ int lc[1024];  // placement cursor
  __shared__ int wsum[256];
  int b = blockIdx.x, t = threadIdx.x;
  int base = b*BCAP;
  int cnt = gbcur[b]; if (cnt > BCAP) cnt = BCAP;
  int nb0 = b*1024;
  for (int i=t;i<1024;i+=256){ lh[i]=0; lc[i]=0; }
  __syncthreads();
  for (int i=t; i<cnt; i+=256) atomicAdd(&lh[tmp[(size_t)base+i] & 1023u], 1);
  __syncthreads();
  int v4[4]; int sum = 0;
  #pragma unroll
  for (int j=0;j<4;j++){ v4[j] = lh[t*4+j]; sum += v4[j]; }
  wsum[t] = sum; __syncthreads();
  for (int off=1; off<256; off<<=1){
    int u = 0; if (t>=off) u = wsum[t-off];
    __syncthreads(); wsum[t] += u; __syncthreads();
  }
  int run = wsum[t] - sum;   // exclusive base for this thread's 4 nodes
  #pragma unroll
  for (int j=0;j<4;j++){ ls[t*4+j] = run; run += v4[j]; }
  __syncthreads();
  #pragma unroll
  for (int j=0;j<4;j++){
    int node = nb0 + t*4 + j;
    if (node < N){ deg[node] = v4[j]; rs[node] = base + ls[t*4+j]; }
  }
  __syncthreads();
  for (int i=t; i<cnt; i+=256){
    unsigned e = tmp[(size_t)base+i];
    int local = e & 1023u;
    int pos = atomicAdd(&lc[local], 1);
    eidx[base + ls[local] + pos] = (int)(e >> 10);
  }
}

// ---- aggregation (fp16 rows, f32 accum): out = (1+eps)*in + sum_{nbr} in[nbr] ----
__global__ __launch_bounds__(256) void k_agg(const unsigned* __restrict__ inp,
                                             unsigned* __restrict__ out,
                                             const float* __restrict__ epsp,
                                             const int* __restrict__ rs, const int* __restrict__ deg,
                                             const int* __restrict__ eidx, int N){
  int gw = (blockIdx.x*256 + threadIdx.x) >> 6;
  int lane = threadIdx.x & 63;
  if (gw >= N) return;
  float sc = 1.0f + *epsp;
  float2 v = uph(inp[(size_t)gw*64 + lane]);
  float a0 = sc * v.x, a1 = sc * v.y;
  int beg = rs[gw], d = deg[gw];
  int i = 0;
  for (; i+8 <= d; i += 8){
    unsigned u[8];
    #pragma unroll
    for (int j=0;j<8;j++) u[j] = inp[(size_t)eidx[beg+i+j]*64 + lane];
    #pragma unroll
    for (int j=0;j<8;j++){ float2 f = uph(u[j]); a0 += f.x; a1 += f.y; }
  }
  for (; i < d; ++i){
    float2 u = uph(inp[(size_t)eidx[beg+i]*64 + lane]);
    a0 += u.x; a1 += u.y;
  }
  out[(size_t)gw*64 + lane] = pkh(a0, a1);
}

// ---------------- MFMA MLP helpers ----------------
// A frag: row = lane&15, k = (lane>>4)*8 + j ; D: col = lane&15, row = (lane>>4)*4 + r
static constexpr int HSTR = 136;             // fp16 row stride in halves
static constexpr int WSLICE = 32*HSTR;       // 32 rows = 8704 B
static constexpr int WSL64 = 64*HSTR;        // 64 rows = 17408 B

// ---- M=64 helpers (k_mlp1: traffic-dominated, 2 stages) ----
__device__ __forceinline__ void load_a_glob4(const _Float16* __restrict__ t, int rbase,
                                             int lane, int N, f16x8 a[4][4]){
  #pragma unroll
  for (int ms=0; ms<4; ++ms){
    int row = rbase + ms*16 + (lane & 15); if (row >= N) row = N - 1;
    const _Float16* ap = t + (size_t)row*128 + ((lane>>4)*8);
    #pragma unroll
    for (int kt=0;kt<4;kt++) a[ms][kt] = *reinterpret_cast<const f16x8*>(ap + kt*32);
  }
}
__device__ __forceinline__ void load_a_lds4(const _Float16* slice, int lane, f16x8 a[4][4]){
  int ko = (lane>>4)*8;
  #pragma unroll
  for (int ms=0; ms<4; ++ms){
    const _Float16* rp = slice + (ms*16 + (lane&15))*HSTR + ko;
    #pragma unroll
    for (int kt=0;kt<4;kt++) a[ms][kt] = *reinterpret_cast<const f16x8*>(rp + kt*32);
  }
}
__device__ __forceinline__ void half_relu64(const f16x8 a[4][4],
                                            const unsigned short* __restrict__ w,
                                            const float* __restrict__ bias,
                                            _Float16* slice, int lane, int hidx){
  const unsigned short* wb = w + (hidx<<14);
  int r0 = (lane>>4)*4, col0 = lane & 15;
  #pragma unroll
  for (int ct4=0; ct4<4; ++ct4){
    f32x4 c[4], d[4];
    #pragma unroll
    for (int m=0;m<4;m++){ c[m] = {0.f,0.f,0.f,0.f}; d[m] = {0.f,0.f,0.f,0.f}; }
    #pragma unroll
    for (int kt=0; kt<4; ++kt){
      const f16x8 bh = *reinterpret_cast<const f16x8*>(wb + ((kt*4+ct4)<<10) + (lane<<3));
      const f16x8 bl = *reinterpret_cast<const f16x8*>(wb + ((kt*4+ct4)<<10) + 512 + (lane<<3));
      #pragma unroll
      for (int m=0;m<4;m++){
        c[m] = __builtin_amdgcn_mfma_f32_16x16x32_f16(a[m][kt], bh, c[m], 0,0,0);
        d[m] = __builtin_amdgcn_mfma_f32_16x16x32_f16(a[m][kt], bl, d[m], 0,0,0);
      }
    }
    float bv = bias[hidx*64 + ct4*16 + col0];
    int cb = hidx*64 + ct4*16 + col0;
    #pragma unroll
    for (int m=0;m<4;m++){
      #pragma unroll
      for (int r=0;r<4;r++){
        float v = fmaxf(c[m][r] + d[m][r]*LO_USCALE + bv, 0.f);
        slice[(m*16 + r0 + r)*HSTR + cb] = (_Float16)v;
      }
    }
  }
}

// ---- M=32 helpers (k_mlp2_head: latency-dominated, 4 stages — needs wave count) ----
__device__ __forceinline__ void load_a_glob2(const _Float16* __restrict__ t, int rbase,
                                             int lane, int N, f16x8 a[2][4]){
  #pragma unroll
  for (int ms=0; ms<2; ++ms){
    int row = rbase + ms*16 + (lane & 15); if (row >= N) row = N - 1;
    const _Float16* ap = t + (size_t)row*128 + ((lane>>4)*8);
    #pragma unroll
    for (int kt=0;kt<4;kt++) a[ms][kt] = *reinterpret_cast<const f16x8*>(ap + kt*32);
  }
}
__device__ __forceinline__ void load_a_lds2(const _Float16* slice, int lane, f16x8 a[2][4]){
  int ko = (lane>>4)*8;
  #pragma unroll
  for (int ms=0; ms<2; ++ms){
    const _Float16* rp = slice + (ms*16 + (lane&15))*HSTR + ko;
    #pragma unroll
    for (int kt=0;kt<4;kt++) a[ms][kt] = *reinterpret_cast<const f16x8*>(rp + kt*32);
  }
}
__device__ __forceinline__ void half_relu(const f16x8 a[2][4],
                                          const unsigned short* __restrict__ w,
                                          const float* __restrict__ bias,
                                          _Float16* slice, int lane, int hidx){
  const unsigned short* wb = w + (hidx<<14);
  int r0 = (lane>>4)*4, col0 = lane & 15;
  #pragma unroll
  for (int ct4=0; ct4<4; ++ct4){
    f32x4 c0={0.f,0.f,0.f,0.f}, c1={0.f,0.f,0.f,0.f};
    f32x4 d0={0.f,0.f,0.f,0.f}, d1={0.f,0.f,0.f,0.f};
    #pragma unroll
    for (int kt=0; kt<4; ++kt){
      const f16x8 bh = *reinterpret_cast<const f16x8*>(wb + ((kt*4+ct4)<<10) + (lane<<3));
      const f16x8 bl = *reinterpret_cast<const f16x8*>(wb + ((kt*4+ct4)<<10) + 512 + (lane<<3));
      c0 = __builtin_amdgcn_mfma_f32_16x16x32_f16(a[0][kt], bh, c0, 0,0,0);
      c1 = __builtin_amdgcn_mfma_f32_16x16x32_f16(a[1][kt], bh, c1, 0,0,0);
      d0 = __builtin_amdgcn_mfma_f32_16x16x32_f16(a[0][kt], bl, d0, 0,0,0);
      d1 = __builtin_amdgcn_mfma_f32_16x16x32_f16(a[1][kt], bl, d1, 0,0,0);
    }
    float bv = bias[hidx*64 + ct4*16 + col0];
    int cb = hidx*64 + ct4*16 + col0;
    #pragma unroll
    for (int r=0;r<4;r++){
      float v0 = fmaxf(c0[r] + d0[r]*LO_USCALE + bv, 0.f);
      float v1 = fmaxf(c1[r] + d1[r]*LO_USCALE + bv, 0.f);
      slice[(r0+r)*HSTR + cb]      = (_Float16)v0;
      slice[(16+r0+r)*HSTR + cb]   = (_Float16)v1;
    }
  }
}
__device__ __forceinline__ void head_sig(const f16x8 a[2][4],
                                         const unsigned short* __restrict__ w,
                                         const float* __restrict__ bias,
                                         float* fs, int lane){
  int r0 = (lane>>4)*4, col0 = lane & 15;
  #pragma unroll
  for (int ct4=0; ct4<4; ++ct4){
    f32x4 c0={0.f,0.f,0.f,0.f}, c1={0.f,0.f,0.f,0.f};
    f32x4 d0={0.f,0.f,0.f,0.f}, d1={0.f,0.f,0.f,0.f};
    #pragma unroll
    for (int kt=0; kt<4; ++kt){
      const f16x8 bh = *reinterpret_cast<const f16x8*>(w + ((kt*4+ct4)<<10) + (lane<<3));
      const f16x8 bl = *reinterpret_cast<const f16x8*>(w + ((kt*4+ct4)<<10) + 512 + (lane<<3));
      c0 = __builtin_amdgcn_mfma_f32_16x16x32_f16(a[0][kt], bh, c0, 0,0,0);
      c1 = __builtin_amdgcn_mfma_f32_16x16x32_f16(a[1][kt], bh, c1, 0,0,0);
      d0 = __builtin_amdgcn_mfma_f32_16x16x32_f16(a[0][kt], bl, d0, 0,0,0);
      d1 = __builtin_amdgcn_mfma_f32_16x16x32_f16(a[1][kt], bl, d1, 0,0,0);
    }
    float bv = bias[ct4*16 + col0];
    int cb = ct4*16 + col0;
    #pragma unroll
    for (int r=0;r<4;r++){
      float z0 = c0[r] + d0[r]*LO_USCALE + bv;
      float z1 = c1[r] + d1[r]*LO_USCALE + bv;
      fs[(r0+r)*68 + cb]    = 1.0f / (1.0f + __expf(-z0));
      fs[(16+r0+r)*68 + cb] = 1.0f / (1.0f + __expf(-z1));
    }
  }
}

// ------------- layer-1 MLP (M=64/wave, 2 waves/block, barrier-free) -------------
__global__ __launch_bounds__(128) void k_mlp1(const _Float16* __restrict__ t,
    const unsigned short* __restrict__ w1, const float* __restrict__ b1,
    const unsigned short* __restrict__ w2, const float* __restrict__ b2,
    unsigned* __restrict__ h, int N){
  __shared__ _Float16 lds[2*WSL64];
  int tid = threadIdx.x, lane = tid & 63, wv = tid >> 6;
  _Float16* slice = lds + wv*WSL64;
  int rbase = blockIdx.x*128 + wv*64;
  f16x8 a[4][4];
  load_a_glob4(t, rbase, lane, N, a);
  half_relu64(a, w1, b1, slice, lane, 0);
  half_relu64(a, w1, b1, slice, lane, 1);
  load_a_lds4(slice, lane, a);
  half_relu64(a, w2, b2, slice, lane, 0);
  half_relu64(a, w2, b2, slice, lane, 1);
  for (int i=lane; i < 64*32; i += 64){
    int r = i >> 5, c = i & 31;
    if (rbase + r < N)
      reinterpret_cast<uint2*>(h)[(size_t)(rbase + r)*32 + c] =
        *reinterpret_cast<const uint2*>(slice + r*HSTR + c*4);
  }
}

// ------- layer-2 MLP + head fused (M=32/wave, 4 waves/block, barrier-free, no setprio) -------
__global__ __launch_bounds__(256) void k_mlp2_head(const _Float16* __restrict__ t,
    const unsigned short* __restrict__ w1, const float* __restrict__ b1,
    const unsigned short* __restrict__ w2, const float* __restrict__ b2,
    const unsigned short* __restrict__ w3, const float* __restrict__ b3,
    const unsigned short* __restrict__ w4, const float* __restrict__ b4,
    float* __restrict__ out, int N){
  __shared__ _Float16 lds[4*WSLICE];
  int tid = threadIdx.x, lane = tid & 63, wv = tid >> 6;
  _Float16* slice = lds + wv*WSLICE;
  int rbase = blockIdx.x*128 + wv*32;
  f16x8 a[2][4];
  load_a_glob2(t, rbase, lane, N, a);
  half_relu(a, w1, b1, slice, lane, 0);
  half_relu(a, w1, b1, slice, lane, 1);
  load_a_lds2(slice, lane, a);
  half_relu(a, w2, b2, slice, lane, 0);
  half_relu(a, w2, b2, slice, lane, 1);
  load_a_lds2(slice, lane, a);
  half_relu(a, w3, b3, slice, lane, 0);
  half_relu(a, w3, b3, slice, lane, 1);
  load_a_lds2(slice, lane, a);
  float* fs = reinterpret_cast<float*>(slice);  // [32][68] f32 = 8704 B = slice
  head_sig(a, w4, b4, fs, lane);
  for (int i=lane; i < 32*16; i += 64){
    int r = i >> 4, c = i & 15;
    if (rbase + r < N){
      f32x4 o = *reinterpret_cast<const f32x4*>(fs + r*68 + c*4);
      __builtin_nontemporal_store(o,
        reinterpret_cast<f32x4*>(out) + (size_t)(rbase + r)*16 + c);   // final out: never re-read
    }
  }
}

// ---------------- host launch ----------------
extern "C" void kernel_launch(void* const* d_in, const int* in_sizes, int n_in,
                              void* d_out, int out_size, void* d_ws, size_t ws_size,
                              hipStream_t stream) {
  const float* x   = (const float*)d_in[0];
  const int*   src = (const int*)  d_in[1];
  const int*   dst = (const int*)  d_in[2];
  const float* eps1= (const float*)d_in[3];
  const float* eps2= (const float*)d_in[4];
  const float* w11 = (const float*)d_in[5];  const float* b11 = (const float*)d_in[6];
  const float* w12 = (const float*)d_in[7];  const float* b12 = (const float*)d_in[8];
  const float* w21 = (const float*)d_in[9];  const float* b21 = (const float*)d_in[10];
  const float* w22 = (const float*)d_in[11]; const float* b22 = (const float*)d_in[12];
  const float* wm1 = (const float*)d_in[13]; const float* bm1 = (const float*)d_in[14];
  const float* wm2 = (const float*)d_in[15]; const float* bm2 = (const float*)d_in[16];

  char* ws = (char*)d_ws;
  size_t off = 0;
  auto alloc = [&](size_t bytes) -> void* {
    void* p = ws + off;
    off = (off + bytes + 255) & ~(size_t)255;
    return p;
  };
  unsigned* xh  = (unsigned*)alloc((size_t)NN*64*4);          // x as fp16 [N][128]
  unsigned* B0  = (unsigned*)alloc((size_t)NN*64*4);          // agg out fp16 (t1 / t2)
  unsigned* h1h = (unsigned*)alloc((size_t)NN*64*4);          // h1 fp16
  unsigned* tmp = (unsigned*)alloc((size_t)NBUK*BCAP*4);      // bucketed (src<<10 | dst&1023)
  int* eidx = (int*)alloc((size_t)NBUK*BCAP*4);
  int* deg  = (int*)alloc((size_t)NN*4);
  int* rs   = (int*)alloc((size_t)NN*4);
  int* gbcur= (int*)alloc((size_t)NBUK*4);
  unsigned short* p11 = (unsigned short*)alloc(128*128*2*2);
  unsigned short* p12 = (unsigned short*)alloc(128*128*2*2);
  unsigned short* p21 = (unsigned short*)alloc(128*128*2*2);
  unsigned short* p22 = (unsigned short*)alloc(128*128*2*2);
  unsigned short* pm1 = (unsigned short*)alloc(128*128*2*2);
  unsigned short* pm2 = (unsigned short*)alloc(128*64*2*2);
  if (off > ws_size) return;   // visible failure if workspace too small

  hipMemsetAsync(gbcur, 0, (size_t)NBUK*4, stream);

  k_pack<<<176, 64, 0, stream>>>(w11,w12,w21,w22,wm1,wm2, p11,p12,p21,p22,pm1,pm2);
  k_cvt<<<(NN*32 + 255)/256, 256, 0, stream>>>(x, xh, NN*32);
  k_scatter1<<<SC_BLOCKS, 256, 0, stream>>>(src, dst, gbcur, tmp);
  k_fill2<<<NBUK, 256, 0, stream>>>(tmp, gbcur, eidx, rs, deg, NN);

  int mgrid = (NN + 127) / 128;
  // layer 1
  k_agg<<<(NN+3)/4, 256, 0, stream>>>(xh, B0, eps1, rs, deg, eidx, NN);
  k_mlp1<<<mgrid, 128, 0, stream>>>((const _Float16*)B0, p11, b11, p12, b12, h1h, NN);
  // layer 2 + head
  k_agg<<<(NN+3)/4, 256, 0, stream>>>(h1h, B0, eps2, rs, deg, eidx, NN);
  k_mlp2_head<<<mgrid, 256, 0, stream>>>((const _Float16*)B0, p21, b21, p22, b22,
                                         pm1, bm1, pm2, bm2, (float*)d_out, NN);
}

// Round 17
// 281.350 us; speedup vs baseline: 1.0636x; 1.0419x over previous
//
#include <hip/hip_runtime.h>

static constexpr int NN = 100000;
static constexpr int NE = 1600000;
static constexpr int NBUK = (NN + 1023) / 1024;      // 98 buckets of 1024 nodes
static constexpr int BCAP = 20480;                   // bucket capacity (mean 16384 + 32 sigma)
static constexpr int SC_BLOCKS = 400;
static constexpr int SC_CH = NE / SC_BLOCKS;         // 4000 edges per block

typedef float     f32x4  __attribute__((ext_vector_type(4)));
typedef _Float16  f16x8  __attribute__((ext_vector_type(8)));

static constexpr float LO_SCALE  = 16384.0f;          // 2^14: keeps w-lo in fp16 normal range
static constexpr float LO_USCALE = 1.0f / 16384.0f;

// fp16 pack/unpack (2 elems per 32-bit word)
__device__ __forceinline__ unsigned pkh(float x, float y){
  unsigned short a = __builtin_bit_cast(unsigned short, (_Float16)x);
  unsigned short b = __builtin_bit_cast(unsigned short, (_Float16)y);
  return (unsigned)a | ((unsigned)b << 16);
}
__device__ __forceinline__ float2 uph(unsigned u){
  _Float16 a = __builtin_bit_cast(_Float16, (unsigned short)(u & 0xffffu));
  _Float16 b = __builtin_bit_cast(_Float16, (unsigned short)(u >> 16));
  return make_float2((float)a, (float)b);
}

// ------------- weight packing: per half-stage contiguous 32KB, hi/lo interleaved -------------
// layout: P[hidx*16384 + (kt*4+ct4)*1024 + hl*512 + lane*8 + j]
// fragment (kt,ct): lane holds B[kt*32+(lane>>4)*8+j][ct*16+(lane&15)], j=0..7
__global__ void k_pack(const float* __restrict__ w11, const float* __restrict__ w12,
                       const float* __restrict__ w21, const float* __restrict__ w22,
                       const float* __restrict__ wm1, const float* __restrict__ wm2,
                       unsigned short* __restrict__ p11, unsigned short* __restrict__ p12,
                       unsigned short* __restrict__ p21, unsigned short* __restrict__ p22,
                       unsigned short* __restrict__ pm1, unsigned short* __restrict__ pm2){
  int b = blockIdx.x, lane = threadIdx.x;
  const float* W; unsigned short* P; int NCT, f;
  if (b < 160){
    int m = b >> 5; f = b & 31; NCT = 8;
    W = (m==0)?w11:(m==1)?w12:(m==2)?w21:(m==3)?w22:wm1;
    P = (m==0)?p11:(m==1)?p12:(m==2)?p21:(m==3)?p22:pm1;
  } else { f = b - 160; NCT = 4; W = wm2; P = pm2; }
  int NC = NCT * 16;
  int kt = f / NCT, ct = f % NCT;
  int hidx = ct >> 2, ct4 = ct & 3;
  int k0 = kt*32 + ((lane>>4)*8), col = ct*16 + (lane&15);
  unsigned short* dh = P + (hidx<<14) + ((kt*4+ct4)<<10) + (lane<<3);
  unsigned short* dl = dh + 512;
  #pragma unroll
  for (int j=0;j<8;j++){
    float v = W[(size_t)(k0+j)*NC + col];
    _Float16 h = (_Float16)v;
    _Float16 l = (_Float16)((v - (float)h) * LO_SCALE);
    dh[j] = __builtin_bit_cast(unsigned short, h);
    dl[j] = __builtin_bit_cast(unsigned short, l);
  }
}

// ---------------- f32 -> fp16 convert ----------------
__global__ void k_cvt(const float* __restrict__ x, unsigned* __restrict__ xh, int n4){
  int i = blockIdx.x*256 + threadIdx.x;
  if (i < n4){
    float4 v = reinterpret_cast<const float4*>(x)[i];
    uint2 o; o.x = pkh(v.x, v.y); o.y = pkh(v.z, v.w);
    reinterpret_cast<uint2*>(xh)[i] = o;
  }
}

// ---------------- CSR build: fixed-capacity buckets, no histogram pass ----------------
__global__ __launch_bounds__(256) void k_scatter1(const int* __restrict__ src,
                                                  const int* __restrict__ dst,
                                                  int* __restrict__ gbcur,
                                                  unsigned* __restrict__ tmp){
  __shared__ int hc[NBUK];
  __shared__ int hb[NBUK];
  int blk = blockIdx.x, t = threadIdx.x;
  int e0 = blk * SC_CH, e1 = e0 + SC_CH;
  for (int i=t;i<NBUK;i+=256) hc[i]=0;
  __syncthreads();
  for (int e=e0+t; e<e1; e+=256) atomicAdd(&hc[((unsigned)dst[e])>>10], 1);
  __syncthreads();
  for (int i=t;i<NBUK;i+=256){ int c = hc[i]; hb[i] = c ? atomicAdd(&gbcur[i], c) : 0; }
  __syncthreads();
  for (int i=t;i<NBUK;i+=256) hc[i]=0;
  __syncthreads();
  for (int e=e0+t; e<e1; e+=256){
    unsigned d = (unsigned)dst[e]; unsigned b = d>>10;
    int pos = hb[b] + atomicAdd(&hc[b], 1);
    if (pos < BCAP)
      tmp[(size_t)b*BCAP + pos] = ((unsigned)src[e] << 10) | (d & 1023u);
  }
}

// one block per 1024-node bucket: LDS counting sort -> eidx, emits deg & rs
__global__ __launch_bounds__(256) void k_fill2(const unsigned* __restrict__ tmp,
                                               const int* __restrict__ gbcur,
                                               int* __restrict__ eidx,
                                               int* __restrict__ rs, int* __restrict__ deg, int N){
  __shared__ int lh[1024];  // per-local-node count
  __shared__ int ls[1024];  // exclusive prefix
  __shared__ int lc[1024];  // placement cursor
  __shared__ int wsum[256];
  int b = blockIdx.x, t = threadIdx.x;
  int base = b*BCAP;
  int cnt = gbcur[b]; if (cnt > BCAP) cnt = BCAP;
  int nb0 = b*1024;
  for (int i=t;i<1024;i+=256){ lh[i]=0; lc[i]=0; }
  __syncthreads();
  for (int i=t; i<cnt; i+=256) atomicAdd(&lh[tmp[(size_t)base+i] & 1023u], 1);
  __syncthreads();
  int v4[4]; int sum = 0;
  #pragma unroll
  for (int j=0;j<4;j++){ v4[j] = lh[t*4+j]; sum += v4[j]; }
  wsum[t] = sum; __syncthreads();
  for (int off=1; off<256; off<<=1){
    int u = 0; if (t>=off) u = wsum[t-off];
    __syncthreads(); wsum[t] += u; __syncthreads();
  }
  int run = wsum[t] - sum;   // exclusive base for this thread's 4 nodes
  #pragma unroll
  for (int j=0;j<4;j++){ ls[t*4+j] = run; run += v4[j]; }
  __syncthreads();
  #pragma unroll
  for (int j=0;j<4;j++){
    int node = nb0 + t*4 + j;
    if (node < N){ deg[node] = v4[j]; rs[node] = base + ls[t*4+j]; }
  }
  __syncthreads();
  for (int i=t; i<cnt; i+=256){
    unsigned e = tmp[(size_t)base+i];
    int local = e & 1023u;
    int pos = atomicAdd(&lc[local], 1);
    eidx[base + ls[local] + pos] = (int)(e >> 10);
  }
}

// ---- aggregation (fp16 rows, f32 accum): out = (1+eps)*in + sum_{nbr} in[nbr] ----
__global__ __launch_bounds__(256) void k_agg(const unsigned* __restrict__ inp,
                                             unsigned* __restrict__ out,
                                             const float* __restrict__ epsp,
                                             const int* __restrict__ rs, const int* __restrict__ deg,
                                             const int* __restrict__ eidx, int N){
  int gw = (blockIdx.x*256 + threadIdx.x) >> 6;
  int lane = threadIdx.x & 63;
  if (gw >= N) return;
  float sc = 1.0f + *epsp;
  float2 v = uph(inp[(size_t)gw*64 + lane]);
  float a0 = sc * v.x, a1 = sc * v.y;
  int beg = rs[gw], d = deg[gw];
  int i = 0;
  for (; i+8 <= d; i += 8){
    unsigned u[8];
    #pragma unroll
    for (int j=0;j<8;j++) u[j] = inp[(size_t)eidx[beg+i+j]*64 + lane];
    #pragma unroll
    for (int j=0;j<8;j++){ float2 f = uph(u[j]); a0 += f.x; a1 += f.y; }
  }
  for (; i < d; ++i){
    float2 u = uph(inp[(size_t)eidx[beg+i]*64 + lane]);
    a0 += u.x; a1 += u.y;
  }
  out[(size_t)gw*64 + lane] = pkh(a0, a1);
}

// ---------------- MFMA MLP helpers (fp16 datapath, M=64/wave) ----------------
// A frag: row = lane&15, k = (lane>>4)*8 + j ; D: col = lane&15, row = (lane>>4)*4 + r
static constexpr int HSTR = 136;             // fp16 row stride in halves
static constexpr int WSL64 = 64*HSTR;        // 64 rows per wave = 17408 B

__device__ __forceinline__ void load_a_glob4(const _Float16* __restrict__ t, int rbase,
                                             int lane, int N, f16x8 a[4][4]){
  #pragma unroll
  for (int ms=0; ms<4; ++ms){
    int row = rbase + ms*16 + (lane & 15); if (row >= N) row = N - 1;
    const _Float16* ap = t + (size_t)row*128 + ((lane>>4)*8);
    #pragma unroll
    for (int kt=0;kt<4;kt++) a[ms][kt] = *reinterpret_cast<const f16x8*>(ap + kt*32);
  }
}
__device__ __forceinline__ void load_a_lds4(const _Float16* slice, int lane, f16x8 a[4][4]){
  int ko = (lane>>4)*8;
  #pragma unroll
  for (int ms=0; ms<4; ++ms){
    const _Float16* rp = slice + (ms*16 + (lane&15))*HSTR + ko;
    #pragma unroll
    for (int kt=0;kt<4;kt++) a[ms][kt] = *reinterpret_cast<const f16x8*>(rp + kt*32);
  }
}

// one 64-col half for 64 rows: out cols [hidx*64, hidx*64+64), relu -> fp16 slice
__device__ __forceinline__ void half_relu64(const f16x8 a[4][4],
                                            const unsigned short* __restrict__ w,
                                            const float* __restrict__ bias,
                                            _Float16* slice, int lane, int hidx){
  const unsigned short* wb = w + (hidx<<14);
  int r0 = (lane>>4)*4, col0 = lane & 15;
  #pragma unroll
  for (int ct4=0; ct4<4; ++ct4){
    f32x4 c[4], d[4];
    #pragma unroll
    for (int m=0;m<4;m++){ c[m] = {0.f,0.f,0.f,0.f}; d[m] = {0.f,0.f,0.f,0.f}; }
    #pragma unroll
    for (int kt=0; kt<4; ++kt){
      const f16x8 bh = *reinterpret_cast<const f16x8*>(wb + ((kt*4+ct4)<<10) + (lane<<3));
      const f16x8 bl = *reinterpret_cast<const f16x8*>(wb + ((kt*4+ct4)<<10) + 512 + (lane<<3));
      #pragma unroll
      for (int m=0;m<4;m++){
        c[m] = __builtin_amdgcn_mfma_f32_16x16x32_f16(a[m][kt], bh, c[m], 0,0,0);
        d[m] = __builtin_amdgcn_mfma_f32_16x16x32_f16(a[m][kt], bl, d[m], 0,0,0);
      }
    }
    float bv = bias[hidx*64 + ct4*16 + col0];
    int cb = hidx*64 + ct4*16 + col0;
    #pragma unroll
    for (int m=0;m<4;m++){
      #pragma unroll
      for (int r=0;r<4;r++){
        float v = fmaxf(c[m][r] + d[m][r]*LO_USCALE + bv, 0.f);
        slice[(m*16 + r0 + r)*HSTR + cb] = (_Float16)v;
      }
    }
  }
}

// head (64 cols) for 64 rows: sigmoid -> f32 staging (stride 68) overlaid on slice
__device__ __forceinline__ void head_sig64(const f16x8 a[4][4],
                                           const unsigned short* __restrict__ w,
                                           const float* __restrict__ bias,
                                           float* fs, int lane){
  int r0 = (lane>>4)*4, col0 = lane & 15;
  #pragma unroll
  for (int ct4=0; ct4<4; ++ct4){
    f32x4 c[4], d[4];
    #pragma unroll
    for (int m=0;m<4;m++){ c[m] = {0.f,0.f,0.f,0.f}; d[m] = {0.f,0.f,0.f,0.f}; }
    #pragma unroll
    for (int kt=0; kt<4; ++kt){
      const f16x8 bh = *reinterpret_cast<const f16x8*>(w + ((kt*4+ct4)<<10) + (lane<<3));
      const f16x8 bl = *reinterpret_cast<const f16x8*>(w + ((kt*4+ct4)<<10) + 512 + (lane<<3));
      #pragma unroll
      for (int m=0;m<4;m++){
        c[m] = __builtin_amdgcn_mfma_f32_16x16x32_f16(a[m][kt], bh, c[m], 0,0,0);
        d[m] = __builtin_amdgcn_mfma_f32_16x16x32_f16(a[m][kt], bl, d[m], 0,0,0);
      }
    }
    float bv = bias[ct4*16 + col0];
    int cb = ct4*16 + col0;
    #pragma unroll
    for (int m=0;m<4;m++){
      #pragma unroll
      for (int r=0;r<4;r++){
        float z = c[m][r] + d[m][r]*LO_USCALE + bv;
        fs[(m*16 + r0 + r)*68 + cb] = 1.0f / (1.0f + __expf(-z));
      }
    }
  }
}

// ------------- layer-1 MLP: h1 = relu(relu(t@w1+b1)@w2+b2), fp16 in/out, barrier-free -------------
__global__ __launch_bounds__(128) void k_mlp1(const _Float16* __restrict__ t,
    const unsigned short* __restrict__ w1, const float* __restrict__ b1,
    const unsigned short* __restrict__ w2, const float* __restrict__ b2,
    unsigned* __restrict__ h, int N){
  __shared__ _Float16 lds[2*WSL64];
  int tid = threadIdx.x, lane = tid & 63, wv = tid >> 6;
  _Float16* slice = lds + wv*WSL64;
  int rbase = blockIdx.x*128 + wv*64;
  f16x8 a[4][4];
  load_a_glob4(t, rbase, lane, N, a);
  half_relu64(a, w1, b1, slice, lane, 0);
  half_relu64(a, w1, b1, slice, lane, 1);
  load_a_lds4(slice, lane, a);
  half_relu64(a, w2, b2, slice, lane, 0);
  half_relu64(a, w2, b2, slice, lane, 1);
  for (int i=lane; i < 64*32; i += 64){
    int r = i >> 5, c = i & 31;
    if (rbase + r < N)
      reinterpret_cast<uint2*>(h)[(size_t)(rbase + r)*32 + c] =
        *reinterpret_cast<const uint2*>(slice + r*HSTR + c*4);
  }
}

// ------- layer-2 MLP + head fused: out = sigmoid(mlp_head(relu(mlp2(t2)))), barrier-free -------
__global__ __launch_bounds__(128) void k_mlp2_head(const _Float16* __restrict__ t,
    const unsigned short* __restrict__ w1, const float* __restrict__ b1,
    const unsigned short* __restrict__ w2, const float* __restrict__ b2,
    const unsigned short* __restrict__ w3, const float* __restrict__ b3,
    const unsigned short* __restrict__ w4, const float* __restrict__ b4,
    float* __restrict__ out, int N){
  __shared__ _Float16 lds[2*WSL64];
  int tid = threadIdx.x, lane = tid & 63, wv = tid >> 6;
  _Float16* slice = lds + wv*WSL64;
  int rbase = blockIdx.x*128 + wv*64;
  f16x8 a[4][4];
  load_a_glob4(t, rbase, lane, N, a);
  half_relu64(a, w1, b1, slice, lane, 0);
  half_relu64(a, w1, b1, slice, lane, 1);
  load_a_lds4(slice, lane, a);
  half_relu64(a, w2, b2, slice, lane, 0);
  half_relu64(a, w2, b2, slice, lane, 1);
  load_a_lds4(slice, lane, a);
  half_relu64(a, w3, b3, slice, lane, 0);
  half_relu64(a, w3, b3, slice, lane, 1);
  load_a_lds4(slice, lane, a);
  float* fs = reinterpret_cast<float*>(slice);  // [64][68] f32 = 17408 B = slice
  head_sig64(a, w4, b4, fs, lane);
  for (int i=lane; i < 64*16; i += 64){
    int r = i >> 4, c = i & 15;
    if (rbase + r < N){
      f32x4 o = *reinterpret_cast<const f32x4*>(fs + r*68 + c*4);
      __builtin_nontemporal_store(o,
        reinterpret_cast<f32x4*>(out) + (size_t)(rbase + r)*16 + c);   // final out: never re-read
    }
  }
}

// ---------------- host launch ----------------
extern "C" void kernel_launch(void* const* d_in, const int* in_sizes, int n_in,
                              void* d_out, int out_size, void* d_ws, size_t ws_size,
                              hipStream_t stream) {
  const float* x   = (const float*)d_in[0];
  const int*   src = (const int*)  d_in[1];
  const int*   dst = (const int*)  d_in[2];
  const float* eps1= (const float*)d_in[3];
  const float* eps2= (const float*)d_in[4];
  const float* w11 = (const float*)d_in[5];  const float* b11 = (const float*)d_in[6];
  const float* w12 = (const float*)d_in[7];  const float* b12 = (const float*)d_in[8];
  const float* w21 = (const float*)d_in[9];  const float* b21 = (const float*)d_in[10];
  const float* w22 = (const float*)d_in[11]; const float* b22 = (const float*)d_in[12];
  const float* wm1 = (const float*)d_in[13]; const float* bm1 = (const float*)d_in[14];
  const float* wm2 = (const float*)d_in[15]; const float* bm2 = (const float*)d_in[16];

  char* ws = (char*)d_ws;
  size_t off = 0;
  auto alloc = [&](size_t bytes) -> void* {
    void* p = ws + off;
    off = (off + bytes + 255) & ~(size_t)255;
    return p;
  };
  unsigned* xh  = (unsigned*)alloc((size_t)NN*64*4);          // x as fp16 [N][128]
  unsigned* B0  = (unsigned*)alloc((size_t)NN*64*4);          // agg out fp16 (t1 / t2)
  unsigned* h1h = (unsigned*)alloc((size_t)NN*64*4);          // h1 fp16
  unsigned* tmp = (unsigned*)alloc((size_t)NBUK*BCAP*4);      // bucketed (src<<10 | dst&1023)
  int* eidx = (int*)alloc((size_t)NBUK*BCAP*4);
  int* deg  = (int*)alloc((size_t)NN*4);
  int* rs   = (int*)alloc((size_t)NN*4);
  int* gbcur= (int*)alloc((size_t)NBUK*4);
  unsigned short* p11 = (unsigned short*)alloc(128*128*2*2);
  unsigned short* p12 = (unsigned short*)alloc(128*128*2*2);
  unsigned short* p21 = (unsigned short*)alloc(128*128*2*2);
  unsigned short* p22 = (unsigned short*)alloc(128*128*2*2);
  unsigned short* pm1 = (unsigned short*)alloc(128*128*2*2);
  unsigned short* pm2 = (unsigned short*)alloc(128*64*2*2);
  if (off > ws_size) return;   // visible failure if workspace too small

  hipMemsetAsync(gbcur, 0, (size_t)NBUK*4, stream);

  k_pack<<<176, 64, 0, stream>>>(w11,w12,w21,w22,wm1,wm2, p11,p12,p21,p22,pm1,pm2);
  k_cvt<<<(NN*32 + 255)/256, 256, 0, stream>>>(x, xh, NN*32);
  k_scatter1<<<SC_BLOCKS, 256, 0, stream>>>(src, dst, gbcur, tmp);
  k_fill2<<<NBUK, 256, 0, stream>>>(tmp, gbcur, eidx, rs, deg, NN);

  int mgrid = (NN + 127) / 128;
  // layer 1
  k_agg<<<(NN+3)/4, 256, 0, stream>>>(xh, B0, eps1, rs, deg, eidx, NN);
  k_mlp1<<<mgrid, 128, 0, stream>>>((const _Float16*)B0, p11, b11, p12, b12, h1h, NN);
  // layer 2 + head
  k_agg<<<(NN+3)/4, 256, 0, stream>>>(h1h, B0, eps2, rs, deg, eidx, NN);
  k_mlp2_head<<<mgrid, 128, 0, stream>>>((const _Float16*)B0, p21, b21, p22, b22,
                                         pm1, bm1, pm2, bm2, (float*)d_out, NN);
}